// Round 1
// baseline (479.679 us; speedup 1.0000x reference)
//
#include <hip/hip_runtime.h>

#define NB_ 3
#define CB 4
#define CH 1440
#define CW 1440
#define NC 32
#define EPSV 1e-3f

// ---------------- kernel 1: build idx_map via atomicMax (numpy last-write-wins) ----
__global__ __launch_bounds__(256) void k_build_map(
    const int* __restrict__ cb, const int* __restrict__ cy, const int* __restrict__ cx,
    int* __restrict__ idx_map, int n)
{
    int i = blockIdx.x * blockDim.x + threadIdx.x;
    if (i < n) {
        long cell = ((long)cb[i] * CH + cy[i]) * CW + cx[i];
        atomicMax(&idx_map[cell], i);
    }
}

// ---------------- kernel 2: compacted rulebook: per point, list of (nidx<<4)|k ------
__global__ __launch_bounds__(256) void k_rulebook(
    const int* __restrict__ cb, const int* __restrict__ cy, const int* __restrict__ cx,
    const int* __restrict__ idx_map, int* __restrict__ rbcnt, int* __restrict__ rbent, int n)
{
    int i = blockIdx.x * blockDim.x + threadIdx.x;
    if (i >= n) return;
    int b = cb[i], y = cy[i], x = cx[i];
    int cnt = 0;
    int base = i * 9;
    #pragma unroll
    for (int k = 0; k < 9; ++k) {
        int dy = k / 3 - 1, dx = k % 3 - 1;
        int ny = y + dy, nx = x + dx;
        if (ny >= 0 && ny < CH && nx >= 0 && nx < CW) {
            int nb = idx_map[((long)b * CH + ny) * CW + nx];
            if (nb >= 0) { rbent[base + cnt] = (nb << 4) | k; ++cnt; }
        }
    }
    rbcnt[i] = cnt;
}

// ---------------- kernel 3: sparse conv + fused BN (+identity) + ReLU ---------------
// lane = output channel o (0..31); 2 points per wave64; 256 threads -> 8 pts/iter.
// W staged transposed [k][o][c] with row padded to 36 floats (16B-aligned rows,
// banks spread for ds_read_b128).
template<bool ADD_ID>
__global__ __launch_bounds__(256) void k_conv(
    const float* __restrict__ in, const float* __restrict__ idn, float* __restrict__ out,
    const float* __restrict__ W,      // [9][32][32] (k,c,o)
    const float* __restrict__ bias,   // [32]
    const float* __restrict__ gamma, const float* __restrict__ beta,
    const float* __restrict__ mean, const float* __restrict__ var,
    const int* __restrict__ rbcnt, const int* __restrict__ rbent, int n)
{
    __shared__ float Wl[9 * 32 * 36]; // 41472 B

    for (int t = threadIdx.x; t < 9 * 32 * 32; t += blockDim.x) {
        int k = t >> 10;
        int c = (t >> 5) & 31;
        int o = t & 31;
        Wl[(k * 32 + o) * 36 + c] = W[t];
    }
    __syncthreads();

    int lane = threadIdx.x & 63;
    int o = lane & 31;
    int half = lane >> 5;
    int waveid = threadIdx.x >> 6;

    // fold BN: y = conv*sc + sh  (bias folded in)
    float sc = gamma[o] * rsqrtf(var[o] + EPSV);
    float sh = (bias[o] - mean[o]) * sc + beta[o];

    int ptsPerBlock = (blockDim.x >> 6) * 2; // 8
    for (int p0 = blockIdx.x * ptsPerBlock; p0 < n; p0 += gridDim.x * ptsPerBlock) {
        int p = p0 + waveid * 2 + half;
        if (p < n) {
            float acc = 0.f;
            int cnt = rbcnt[p];
            const int* ent = rbent + p * 9;
            for (int e = 0; e < cnt; ++e) {
                int en = ent[e];
                int k = en & 15;
                int idx = en >> 4;
                const float4* xp = (const float4*)(in + (size_t)idx * NC);
                const float4* wp = (const float4*)(&Wl[(k * 32 + o) * 36]);
                #pragma unroll
                for (int j = 0; j < 8; ++j) {
                    float4 xv = xp[j];
                    float4 wv = wp[j];
                    acc += xv.x * wv.x + xv.y * wv.y + xv.z * wv.z + xv.w * wv.w;
                }
            }
            float y = acc * sc + sh;
            if (ADD_ID) y += idn[(size_t)p * NC + o];
            out[(size_t)p * NC + o] = fmaxf(y, 0.f);
        }
    }
}

extern "C" void kernel_launch(void* const* d_in, const int* in_sizes, int n_in,
                              void* d_out, int out_size, void* d_ws, size_t ws_size,
                              hipStream_t stream)
{
    const float* feats = (const float*)d_in[0];
    const float* Wk    = (const float*)d_in[1];  // [3][2][9][32][32]
    const float* bias  = (const float*)d_in[2];  // [3][2][32]
    const float* gamma = (const float*)d_in[3];
    const float* beta  = (const float*)d_in[4];
    const float* mean  = (const float*)d_in[5];
    const float* var   = (const float*)d_in[6];
    const int* cb = (const int*)d_in[7];
    const int* cy = (const int*)d_in[8];
    const int* cx = (const int*)d_in[9];
    float* out = (float*)d_out;
    int n = in_sizes[0] / NC;

    char* ws = (char*)d_ws;
    int*   idx_map = (int*)(ws + 0);                       // 33,177,600 B
    int*   rbcnt   = (int*)(ws + 33177600);                // 800,000 B
    int*   rbent   = (int*)(ws + 33977600);                // 7,200,000 B
    float* tmp     = (float*)(ws + 41177600);              // 25,600,000 B
    float* hbuf    = (float*)(ws + 66777600);              // 25,600,000 B

    hipMemsetAsync(idx_map, 0xFF, (size_t)CB * CH * CW * sizeof(int), stream);

    int blocks = (n + 255) / 256;
    k_build_map<<<blocks, 256, 0, stream>>>(cb, cy, cx, idx_map, n);
    k_rulebook<<<blocks, 256, 0, stream>>>(cb, cy, cx, idx_map, rbcnt, rbent, n);

    const int CONV_GRID = 768; // 3 blocks/CU (LDS-limited) x 256 CU
    const float* hin = feats;
    for (int i = 0; i < NB_; ++i) {
        int l1 = i * 2 + 0, l2 = i * 2 + 1;
        k_conv<false><<<CONV_GRID, 256, 0, stream>>>(
            hin, nullptr, tmp,
            Wk + (size_t)l1 * 9 * 32 * 32, bias + l1 * 32,
            gamma + l1 * 32, beta + l1 * 32, mean + l1 * 32, var + l1 * 32,
            rbcnt, rbent, n);
        float* outp = (i == NB_ - 1) ? out : hbuf;
        k_conv<true><<<CONV_GRID, 256, 0, stream>>>(
            tmp, hin, outp,
            Wk + (size_t)l2 * 9 * 32 * 32, bias + l2 * 32,
            gamma + l2 * 32, beta + l2 * 32, mean + l2 * 32, var + l2 * 32,
            rbcnt, rbent, n);
        hin = (i == NB_ - 1) ? out : hbuf;
    }
}

// Round 2
// 342.621 us; speedup vs baseline: 1.4000x; 1.4000x over previous
//
#include <hip/hip_runtime.h>

#define NB_ 3
#define CB 4
#define CH 1440
#define CW 1440
#define NC 32
#define EPSV 1e-3f

// ---------------- kernel 1: build idx_map via atomicMax (numpy last-write-wins) ----
__global__ __launch_bounds__(256) void k_build_map(
    const int* __restrict__ cb, const int* __restrict__ cy, const int* __restrict__ cx,
    int* __restrict__ idx_map, int n)
{
    int i = blockIdx.x * blockDim.x + threadIdx.x;
    if (i < n) {
        long cell = ((long)cb[i] * CH + cy[i]) * CW + cx[i];
        atomicMax(&idx_map[cell], i);
    }
}

// ---------------- kernel 2: rulebook. meta[p]={selfidx,cnt}; rbent: non-self only --
__global__ __launch_bounds__(256) void k_rulebook(
    const int* __restrict__ cb, const int* __restrict__ cy, const int* __restrict__ cx,
    const int* __restrict__ idx_map, int2* __restrict__ meta, int* __restrict__ rbent, int n)
{
    int i = blockIdx.x * blockDim.x + threadIdx.x;
    if (i >= n) return;
    int b = cb[i], y = cy[i], x = cx[i];
    int s = idx_map[((long)b * CH + y) * CW + x];   // may differ from i on dup coords
    int cnt = 0;
    int base = i * 8;
    #pragma unroll
    for (int k = 0; k < 9; ++k) {
        if (k == 4) continue;
        int dy = k / 3 - 1, dx = k % 3 - 1;
        int ny = y + dy, nx = x + dx;
        if (ny >= 0 && ny < CH && nx >= 0 && nx < CW) {
            int nb = idx_map[((long)b * CH + ny) * CW + nx];
            if (nb >= 0) {
                int kk = (k < 4) ? k : k - 1;       // compacted 0..7 (skip self)
                rbent[base + cnt] = (nb << 3) | kk;
                ++cnt;
            }
        }
    }
    meta[i] = make_int2(s, cnt);
}

// ---------------- kernel 3: sparse conv + fused BN (+identity) + ReLU ---------------
// lane = output channel o; half-wave owns 2 points (4 pts/wave, 16/block-iter).
// Self (k=4) W column held in 32 VGPRs -> dense GEMV needs no LDS/rulebook deps.
// Non-self W (8 offsets) in LDS, rows padded to 36 floats for bank spread.
template<bool ADD_ID>
__global__ __launch_bounds__(256, 4) void k_conv(
    const float* __restrict__ in, const float* __restrict__ idn, float* __restrict__ out,
    const float* __restrict__ W,      // [9][32][32] (k,c,o)
    const float* __restrict__ bias,
    const float* __restrict__ gamma, const float* __restrict__ beta,
    const float* __restrict__ mean, const float* __restrict__ var,
    const int2* __restrict__ meta, const int* __restrict__ rbent, int n)
{
    __shared__ float Wl[8 * 32 * 36]; // 36,864 B -> 4 blocks/CU

    int o = threadIdx.x & 31;

    for (int t = threadIdx.x; t < 8 * 32 * 32; t += 256) {
        int kk = t >> 10;
        int c = (t >> 5) & 31;
        int oo = t & 31;
        int k = (kk < 4) ? kk : kk + 1;
        Wl[(kk * 32 + oo) * 36 + c] = W[k * 1024 + c * 32 + oo];
    }

    // self weight column in registers: w4[c] = W[4][c][o]
    float w4[32];
    #pragma unroll
    for (int c = 0; c < 32; ++c) w4[c] = W[4 * 1024 + c * 32 + o];

    __syncthreads();

    int half = (threadIdx.x >> 5) & 1;
    int waveid = threadIdx.x >> 6;
    int unit = waveid * 2 + half;          // 0..7

    float sc = gamma[o] * rsqrtf(var[o] + EPSV);
    float sh = (bias[o] - mean[o]) * sc + beta[o];

    const int PPB = 16;
    for (int p0 = blockIdx.x * PPB; p0 < n; p0 += gridDim.x * PPB) {
        int pA = p0 + unit * 2;
        int pB = pA + 1;
        bool vA = pA < n, vB = pB < n;

        int2 mA = vA ? meta[pA] : make_int2(0, 0);
        int2 mB = vB ? meta[pB] : make_int2(0, 0);

        const float4* xpA = (const float4*)(in + (size_t)mA.x * NC);
        const float4* xpB = (const float4*)(in + (size_t)mB.x * NC);

        float accA = 0.f, accB = 0.f;
        #pragma unroll
        for (int j = 0; j < 8; ++j) {
            float4 a = vA ? xpA[j] : make_float4(0, 0, 0, 0);
            float4 b = vB ? xpB[j] : make_float4(0, 0, 0, 0);
            accA += a.x * w4[4*j] + a.y * w4[4*j+1] + a.z * w4[4*j+2] + a.w * w4[4*j+3];
            accB += b.x * w4[4*j] + b.y * w4[4*j+1] + b.z * w4[4*j+2] + b.w * w4[4*j+3];
        }

        // rare neighbor entries
        for (int e = 0; e < mA.y; ++e) {
            int en = rbent[pA * 8 + e];
            int kk = en & 7, idx = en >> 3;
            const float4* xp = (const float4*)(in + (size_t)idx * NC);
            const float4* wp = (const float4*)(&Wl[(kk * 32 + o) * 36]);
            #pragma unroll
            for (int j = 0; j < 8; ++j) {
                float4 xv = xp[j], wv = wp[j];
                accA += xv.x * wv.x + xv.y * wv.y + xv.z * wv.z + xv.w * wv.w;
            }
        }
        for (int e = 0; e < mB.y; ++e) {
            int en = rbent[pB * 8 + e];
            int kk = en & 7, idx = en >> 3;
            const float4* xp = (const float4*)(in + (size_t)idx * NC);
            const float4* wp = (const float4*)(&Wl[(kk * 32 + o) * 36]);
            #pragma unroll
            for (int j = 0; j < 8; ++j) {
                float4 xv = xp[j], wv = wp[j];
                accB += xv.x * wv.x + xv.y * wv.y + xv.z * wv.z + xv.w * wv.w;
            }
        }

        if (vA) {
            float y = accA * sc + sh;
            if (ADD_ID) y += idn[(size_t)pA * NC + o];
            out[(size_t)pA * NC + o] = fmaxf(y, 0.f);
        }
        if (vB) {
            float y = accB * sc + sh;
            if (ADD_ID) y += idn[(size_t)pB * NC + o];
            out[(size_t)pB * NC + o] = fmaxf(y, 0.f);
        }
    }
}

extern "C" void kernel_launch(void* const* d_in, const int* in_sizes, int n_in,
                              void* d_out, int out_size, void* d_ws, size_t ws_size,
                              hipStream_t stream)
{
    const float* feats = (const float*)d_in[0];
    const float* Wk    = (const float*)d_in[1];  // [3][2][9][32][32]
    const float* bias  = (const float*)d_in[2];
    const float* gamma = (const float*)d_in[3];
    const float* beta  = (const float*)d_in[4];
    const float* mean  = (const float*)d_in[5];
    const float* var   = (const float*)d_in[6];
    const int* cb = (const int*)d_in[7];
    const int* cy = (const int*)d_in[8];
    const int* cx = (const int*)d_in[9];
    float* out = (float*)d_out;
    int n = in_sizes[0] / NC;

    char* ws = (char*)d_ws;
    int*   idx_map = (int*)(ws + 0);                       // 33,177,600 B
    int2*  meta    = (int2*)(ws + 33177600);               // 1,600,000 B
    int*   rbent   = (int*)(ws + 34777600);                // 6,400,000 B
    float* tmp     = (float*)(ws + 41177600);              // 25,600,000 B
    float* hbuf    = (float*)(ws + 66777600);              // 25,600,000 B

    hipMemsetAsync(idx_map, 0xFF, (size_t)CB * CH * CW * sizeof(int), stream);

    int blocks = (n + 255) / 256;
    k_build_map<<<blocks, 256, 0, stream>>>(cb, cy, cx, idx_map, n);
    k_rulebook<<<blocks, 256, 0, stream>>>(cb, cy, cx, idx_map, meta, rbent, n);

    const int CONV_GRID = 1024; // 4 blocks/CU
    const float* hin = feats;
    for (int i = 0; i < NB_; ++i) {
        int l1 = i * 2 + 0, l2 = i * 2 + 1;
        k_conv<false><<<CONV_GRID, 256, 0, stream>>>(
            hin, nullptr, tmp,
            Wk + (size_t)l1 * 9 * 32 * 32, bias + l1 * 32,
            gamma + l1 * 32, beta + l1 * 32, mean + l1 * 32, var + l1 * 32,
            meta, rbent, n);
        float* outp = (i == NB_ - 1) ? out : hbuf;
        k_conv<true><<<CONV_GRID, 256, 0, stream>>>(
            tmp, hin, outp,
            Wk + (size_t)l2 * 9 * 32 * 32, bias + l2 * 32,
            gamma + l2 * 32, beta + l2 * 32, mean + l2 * 32, var + l2 * 32,
            meta, rbent, n);
        hin = (i == NB_ - 1) ? out : hbuf;
    }
}